// Round 3
// baseline (299.830 us; speedup 1.0000x reference)
//
#include <hip/hip_runtime.h>
#include <math.h>

#define N_BINS_MAX 1024
#define EPS 1e-4f

// Native clang vector types — __builtin_nontemporal_* requires these
// (HIP's int4/float4 are structs and are rejected).
typedef int   vi4 __attribute__((ext_vector_type(4)));
typedef float vf4 __attribute__((ext_vector_type(4)));

__global__ __launch_bounds__(256) void pm_kernel(
    const float* __restrict__ bin_centers, int n_bins,
    const int* __restrict__ idx,
    const float* __restrict__ lb,
    const float* __restrict__ ub,
    float* __restrict__ out,
    long long n_rows)
{
    __shared__ float tab0[N_BINS_MAX];
    __shared__ float tab1[N_BINS_MAX];
    __shared__ float tab2[N_BINS_MAX];

    const float lb0 = lb[0], lb1 = lb[1], lb2 = lb[2];
    const float ub0 = ub[0], ub1 = ub[1], ub2 = ub[2];
    const float r0 = 1.0f / (ub0 - lb0 + EPS);
    const float r1 = 1.0f / (ub1 - lb1 + EPS);
    const float r2 = 1.0f / (ub2 - lb2 + EPS);

    // Per-column sigmoid LUTs: 1024 bins x 3 = 12 KB LDS. Hardware
    // transcendentals (v_log_f32 / v_exp_f32): ~1e-6 rel err, threshold 6e-3.
    for (int i = threadIdx.x; i < n_bins; i += blockDim.x) {
        float c = bin_centers[i];
        float logit = __logf(c / (1.0f - c));
        tab0[i] = 1.0f / (1.0f + __expf(-(ub0 - logit) * r0));
        tab1[i] = 1.0f / (1.0f + __expf(-(ub1 - logit) * r1));
        tab2[i] = 1.0f / (1.0f + __expf(-(ub2 - logit) * r2));
    }
    __syncthreads();

    // Hot loop: 4 rows (one "quad") per iteration. 12 consecutive ints =
    // three aligned dwordx4 loads (48 B/lane), one dwordx4 store. Streaming
    // data is touch-once -> nontemporal (nt) to avoid polluting L2.
    const long long n_quads = n_rows >> 2;
    const vi4* __restrict__ idx4 = (const vi4*)idx;
    vf4* __restrict__ out4 = (vf4*)out;
    const long long stride = (long long)gridDim.x * blockDim.x;

    for (long long q = (long long)blockIdx.x * blockDim.x + threadIdx.x;
         q < n_quads; q += stride) {
        vi4 a = __builtin_nontemporal_load(&idx4[3 * q + 0]);
        vi4 b = __builtin_nontemporal_load(&idx4[3 * q + 1]);
        vi4 c = __builtin_nontemporal_load(&idx4[3 * q + 2]);
        vf4 r;
        r.x = tab0[a.x] * tab1[a.y] * tab2[a.z];
        r.y = tab0[a.w] * tab1[b.x] * tab2[b.y];
        r.z = tab0[b.z] * tab1[b.w] * tab2[c.x];
        r.w = tab0[c.y] * tab1[c.z] * tab2[c.w];
        __builtin_nontemporal_store(r, &out4[q]);
    }

    // Tail rows (n_rows % 4) — none at the bench shape.
    const long long tail_start = n_quads << 2;
    for (long long row = tail_start + (long long)blockIdx.x * blockDim.x + threadIdx.x;
         row < n_rows; row += stride) {
        int i0 = idx[3 * row + 0];
        int i1 = idx[3 * row + 1];
        int i2 = idx[3 * row + 2];
        out[row] = tab0[i0] * tab1[i1] * tab2[i2];
    }
}

extern "C" void kernel_launch(void* const* d_in, const int* in_sizes, int n_in,
                              void* d_out, int out_size, void* d_ws, size_t ws_size,
                              hipStream_t stream) {
    const float* bin_centers = (const float*)d_in[0];
    const int*   idx         = (const int*)d_in[1];
    const float* lb          = (const float*)d_in[2];
    const float* ub          = (const float*)d_in[3];
    // d_in[4] = operator_number (unused by the math)
    float* out = (float*)d_out;

    int n_bins = in_sizes[0];
    long long n_rows = (long long)in_sizes[1] / 3;

    // grid = 2048: 8 quads/thread amortizes the LDS LUT build 8x vs a
    // thread-per-quad launch, while 2048 blocks x 4 waves = 8192 waves still
    // oversubscribes 256 CUs for latency hiding.
    const int block = 256;
    long long n_quads = n_rows >> 2;
    long long want = (n_quads + block - 1) / block;
    if (want < 1) want = 1;
    int grid = (int)((want > 2048) ? 2048 : want);

    pm_kernel<<<grid, block, 0, stream>>>(bin_centers, n_bins, idx, lb, ub, out, n_rows);
}